// Round 5
// baseline (242.757 us; speedup 1.0000x reference)
//
#include <hip/hip_runtime.h>

typedef short s16x8 __attribute__((ext_vector_type(8)));
typedef float f32x4 __attribute__((ext_vector_type(4)));
typedef unsigned short us;

__device__ inline us f2bf(float f){
    union{float f;unsigned u;} v{f};
    unsigned r = v.u + 0x7fff + ((v.u>>16)&1);
    return (us)(r>>16);
}

__device__ __forceinline__ void glds16(const us* g, us* l){
    __builtin_amdgcn_global_load_lds(
        (const __attribute__((address_space(1))) unsigned int*)(g),
        (__attribute__((address_space(3))) unsigned int*)(l), 16, 0, 0);
}

// ---------------- fused cast: x, wqkv_w, wp_w -> bf16, one launch ----------------
__global__ void cast_all(const float* __restrict__ x, const float* __restrict__ wqkv_w,
                         const float* __restrict__ wp_w, us* __restrict__ xbf,
                         us* __restrict__ wqkvbf, us* __restrict__ wpbf){
    int i = blockIdx.x*blockDim.x + threadIdx.x;   // 4456448 float4s
    const float* s; us* d; int j;
    if(i < 4194304){ s = x; d = xbf; j = i; }
    else if(i < 4390912){ s = wqkv_w; d = wqkvbf; j = i - 4194304; }
    else { s = wp_w; d = wpbf; j = i - 4390912; }
    float4 f = ((const float4*)s)[j];
    ushort4 o;
    o.x = f2bf(f.x); o.y = f2bf(f.y); o.z = f2bf(f.z); o.w = f2bf(f.w);
    ((ushort4*)d)[j] = o;
}

// ---- qkv = xbf @ wqkv^T + b  (M=32768,N=1536,K=512). Round-0 128x128 structure
// (4 blocks/CU TLP) + swapped-operand MFMA -> ushort4 stores (verified r4:
// 71.5us, FETCH 29.5MB, WRITE 115MB). ----
__launch_bounds__(256,4)
__global__ void gemm_qkv(const us* __restrict__ A, const us* __restrict__ B,
                         const float* __restrict__ bias, us* __restrict__ C){
    __shared__ __attribute__((aligned(16))) us sA[128*64];
    __shared__ __attribute__((aligned(16))) us sB[128*64];
    int t = threadIdx.x;
    int id = blockIdx.x;                 // 3072
    int xcd = id & 7, s = id >> 3;
    int nt = s % 12, mt = xcd*32 + s/12;
    int lane = t&63, wave = t>>6, quad = lane>>4, l15 = lane&15;
    int wm = wave>>1, wn = wave&1;

    int l8 = lane>>3;
    int sw = ((lane&7) ^ l8)*8;
    const us* Ag = A + (size_t)(mt*128 + wave*32 + l8)*512 + sw;
    const us* Bg = B + (size_t)(nt*128 + wave*32 + l8)*512 + sw;
    us* sAw = &sA[(wave*32)*64];
    us* sBw = &sB[(wave*32)*64];

    f32x4 acc[4][4];
    #pragma unroll
    for(int i=0;i<4;i++)
        #pragma unroll
        for(int j=0;j<4;j++) acc[i][j] = (f32x4){0.f,0.f,0.f,0.f};

    for(int k0=0; k0<512; k0+=64){
        glds16(Ag + k0,           sAw);
        glds16(Ag + 8*512 + k0,   sAw + 8*64);
        glds16(Ag + 16*512 + k0,  sAw + 16*64);
        glds16(Ag + 24*512 + k0,  sAw + 24*64);
        glds16(Bg + k0,           sBw);
        glds16(Bg + 8*512 + k0,   sBw + 8*64);
        glds16(Bg + 16*512 + k0,  sBw + 16*64);
        glds16(Bg + 24*512 + k0,  sBw + 24*64);
        __syncthreads();
        #pragma unroll
        for(int ks=0; ks<2; ks++){
            int kc = ks*4 + quad;
            s16x8 af[4], bfr[4];
            #pragma unroll
            for(int i=0;i<4;i++){
                int r = wm*64 + i*16 + l15;
                af[i] = *(const s16x8*)&sA[r*64 + ((kc ^ (r&7))<<3)];
            }
            #pragma unroll
            for(int j=0;j<4;j++){
                int r = wn*64 + j*16 + l15;
                bfr[j] = *(const s16x8*)&sB[r*64 + ((kc ^ (r&7))<<3)];
            }
            #pragma unroll
            for(int i=0;i<4;i++)
                #pragma unroll
                for(int j=0;j<4;j++)
                    acc[i][j] = __builtin_amdgcn_mfma_f32_16x16x32_bf16(bfr[j], af[i], acc[i][j], 0,0,0);
        }
        __syncthreads();
    }

    // swapped layout: lane holds row = row0+i*16+l15, cols = col0+j*16+quad*4..+3
    int row0 = mt*128 + wm*64, col0 = nt*128 + wn*64;
    float4 bv[4];
    #pragma unroll
    for(int j=0;j<4;j++) bv[j] = *(const float4*)&bias[col0 + j*16 + quad*4];
    #pragma unroll
    for(int i=0;i<4;i++){
        size_t rb = (size_t)(row0 + i*16 + l15)*1536 + col0;
        #pragma unroll
        for(int j=0;j<4;j++){
            ushort4 o;
            o.x = f2bf(acc[i][j][0] + bv[j].x);
            o.y = f2bf(acc[i][j][1] + bv[j].y);
            o.z = f2bf(acc[i][j][2] + bv[j].z);
            o.w = f2bf(acc[i][j][3] + bv[j].w);
            *(ushort4*)&C[rb + j*16 + quad*4] = o;
        }
    }
}

// ---- scores: Spart[kb][head][d][e] partial over 512 tokens (kb<8, 8 chunks).
// LDS double-buffered, ONE barrier per chunk (was 2): iter c issues chunk c+1
// loads (single reg set -- chunk c's regs already in LDS), computes chunk c
// from buf[c&1] (load latency hidden under MFMA), writes regs->buf[(c+1)&1],
// barriers once. LDS 36.9KB -> 4 blocks/CU. ----
__launch_bounds__(256,4)
__global__ void attn_scores_mfma(const us* __restrict__ qkv, float* __restrict__ Sp){
    __shared__ __attribute__((aligned(16))) us sQt[2][64*72];
    __shared__ __attribute__((aligned(16))) us sKt[2][64*72];
    int t = threadIdx.x;
    int kb = blockIdx.x, head = blockIdx.y;   // kb < 8
    int lane = t & 63, w = t >> 6;
    int quad = lane >> 4, l15 = lane & 15;
    int p = t & 31;
    int d0 = (t >> 5) * 8;

    f32x4 acc[4];
    #pragma unroll
    for(int j=0;j<4;j++) acc[j] = (f32x4){0.f,0.f,0.f,0.f};

    const us* gbase = qkv + (size_t)(head*512 + kb*64 + (p>>2))*1536 + (2*(p&3))*64 + d0;
    union U{uint4 v; us h[8];};
    U q0,q1,k0,k1;
    // prologue: chunk 0 -> buf0
    q0.v = *(const uint4*)gbase;         q1.v = *(const uint4*)(gbase + 64);
    k0.v = *(const uint4*)(gbase + 512); k1.v = *(const uint4*)(gbase + 576);
    #pragma unroll
    for(int j=0;j<8;j++){
        *(unsigned*)&sQt[0][(d0+j)*72 + 2*p] = (unsigned)q0.h[j] | ((unsigned)q1.h[j]<<16);
        *(unsigned*)&sKt[0][(d0+j)*72 + 2*p] = (unsigned)k0.h[j] | ((unsigned)k1.h[j]<<16);
    }
    __syncthreads();

    #pragma unroll
    for(int c=0; c<8; c++){
        if(c<7){   // issue next chunk's loads; latency hides under this chunk's MFMAs
            const us* g = gbase + (size_t)(c+1)*8*1536;
            q0.v = *(const uint4*)g;         q1.v = *(const uint4*)(g + 64);
            k0.v = *(const uint4*)(g + 512); k1.v = *(const uint4*)(g + 576);
        }
        const us* Q = sQt[c&1];
        const us* K = sKt[c&1];
        int d = w*16 + l15;
        #pragma unroll
        for(int ks=0; ks<2; ks++){
            int tb = ks*4 + quad;
            s16x8 af = *(const s16x8*)&Q[d*72 + tb*8];
            #pragma unroll
            for(int jt=0; jt<4; jt++){
                s16x8 bfv = *(const s16x8*)&K[(jt*16+l15)*72 + tb*8];
                acc[jt] = __builtin_amdgcn_mfma_f32_16x16x32_bf16(af, bfv, acc[jt], 0,0,0);
            }
        }
        if(c<7){
            int nb = (c+1)&1;
            #pragma unroll
            for(int j=0;j<8;j++){
                *(unsigned*)&sQt[nb][(d0+j)*72 + 2*p] = (unsigned)q0.h[j] | ((unsigned)q1.h[j]<<16);
                *(unsigned*)&sKt[nb][(d0+j)*72 + 2*p] = (unsigned)k0.h[j] | ((unsigned)k1.h[j]<<16);
            }
        }
        __syncthreads();
    }

    float* S = Sp + (size_t)(kb*64 + head)*4096;
    #pragma unroll
    for(int jt=0; jt<4; jt++){
        int e = jt*16 + l15;
        #pragma unroll
        for(int r=0; r<4; r++){
            int d = w*16 + quad*4 + r;
            S[d*64 + e] = acc[jt][r];
        }
    }
}

// ---- sum 8 partials, softmax over e (scale 1/8); 256 blocks (4 d-strips/head) ----
__global__ void softmax64(const float* __restrict__ Sp, us* __restrict__ W){
    int head = blockIdx.x>>2, part = blockIdx.x&3;
    int t = threadIdx.x;           // 256
    int d = part*16 + (t>>4), e0 = (t&15)*4;
    float4 v = {0.f,0.f,0.f,0.f};
    for(int kb=0; kb<8; kb++){
        float4 f = *(const float4*)&Sp[(size_t)(kb*64 + head)*4096 + d*64 + e0];
        v.x+=f.x; v.y+=f.y; v.z+=f.z; v.w+=f.w;
    }
    v.x*=0.125f; v.y*=0.125f; v.z*=0.125f; v.w*=0.125f;
    float m = fmaxf(fmaxf(v.x,v.y), fmaxf(v.z,v.w));
    m = fmaxf(m, __shfl_xor(m, 1));
    m = fmaxf(m, __shfl_xor(m, 2));
    m = fmaxf(m, __shfl_xor(m, 4));
    m = fmaxf(m, __shfl_xor(m, 8));
    v.x=__expf(v.x-m); v.y=__expf(v.y-m); v.z=__expf(v.z-m); v.w=__expf(v.w-m);
    float s = v.x+v.y+v.z+v.w;
    s += __shfl_xor(s, 1);
    s += __shfl_xor(s, 2);
    s += __shfl_xor(s, 4);
    s += __shfl_xor(s, 8);
    float inv = 1.f/s;
    union{uint2 u; us h[4];} o;
    o.h[0]=f2bf(v.x*inv); o.h[1]=f2bf(v.y*inv); o.h[2]=f2bf(v.z*inv); o.h[3]=f2bf(v.w*inv);
    *(uint2*)&W[(size_t)head*4096 + d*64 + e0] = o.u;
}

// ---- M_{b,h}[nO,e] = sum_d wp[nO,h*64+d]*W[d,e]; 256 blocks (4 per head) ----
__launch_bounds__(256,2)
__global__ void fold(const us* __restrict__ Wsm, const us* __restrict__ wpbf,
                     us* __restrict__ Mcat){
    __shared__ us sWt[64*72];   // W^T: sWt[e][d]
    int t = threadIdx.x;
    int head = blockIdx.x>>2, part = blockIdx.x&3;
    int b = head>>3, h = head&7;
    int lane = t&63, w = t>>6, quad = lane>>4, l15 = lane&15;
    #pragma unroll
    for(int it=0; it<2; it++){
        int idx = it*2048 + t*8;
        int d = idx>>6, e0 = idx&63;
        union{uint4 v; us s[8];} q;
        q.v = *(const uint4*)&Wsm[(size_t)head*4096 + idx];
        #pragma unroll
        for(int j=0;j<8;j++) sWt[(e0+j)*72 + d] = q.s[j];
    }
    __syncthreads();
    #pragma unroll
    for(int i=0;i<2;i++){
        int nO = part*128 + w*32 + i*16 + l15;
        s16x8 af0 = *(const s16x8*)&wpbf[(size_t)nO*512 + h*64 + quad*8];
        s16x8 af1 = *(const s16x8*)&wpbf[(size_t)nO*512 + h*64 + 32 + quad*8];
        #pragma unroll
        for(int j=0;j<4;j++){
            s16x8 bf0 = *(const s16x8*)&sWt[(j*16+l15)*72 + quad*8];
            s16x8 bf1 = *(const s16x8*)&sWt[(j*16+l15)*72 + 32 + quad*8];
            f32x4 acc = (f32x4){0.f,0.f,0.f,0.f};
            acc = __builtin_amdgcn_mfma_f32_16x16x32_bf16(af0, bf0, acc, 0,0,0);
            acc = __builtin_amdgcn_mfma_f32_16x16x32_bf16(af1, bf1, acc, 0,0,0);
            #pragma unroll
            for(int r=0;r<4;r++){
                int row = part*128 + w*32 + i*16 + quad*4 + r;
                Mcat[((size_t)(b*512 + row))*512 + h*64 + j*16 + l15] = f2bf(acc[r]);
            }
        }
    }
}

// ---- out_b = Vgather_b @ Mcat_b^T + wp_b. Round-0 structure + swapped MFMA
// epilogue -> float4 stores. ----
__launch_bounds__(256,4)
__global__ void gemm_vout(const us* __restrict__ qkv, const us* __restrict__ Mcat,
                          const float* __restrict__ bias, float* __restrict__ out){
    __shared__ __attribute__((aligned(16))) us sA[128*64];
    __shared__ __attribute__((aligned(16))) us sB[128*64];
    int t = threadIdx.x;
    int id = blockIdx.x;                 // 1024
    int xcd = id & 7, s = id >> 3;
    int nt = s & 3, mt = xcd*32 + (s>>2);
    int b = mt>>5, mr = mt&31;
    int lane = t&63, wave = t>>6, quad = lane>>4, l15 = lane&15;
    int wm = wave>>1, wn = wave&1;

    int l8 = lane>>3;
    int sw = ((lane&7) ^ l8)*8;
    const us* Abase = qkv + ((size_t)(8*b)*512 + mr*16 + wave*4)*1536 + 1024 + l8*64 + sw;
    const us* Bbase = Mcat + ((size_t)(b*512 + nt*128 + wave*32 + l8))*512 + sw;
    us* sAw = &sA[(wave*32)*64];
    us* sBw = &sB[(wave*32)*64];

    f32x4 acc[4][4];
    #pragma unroll
    for(int i=0;i<4;i++)
        #pragma unroll
        for(int j=0;j<4;j++) acc[i][j] = (f32x4){0.f,0.f,0.f,0.f};

    for(int h=0; h<8; h++){
        const us* Ah = Abase + (size_t)h*512*1536;
        const us* Bh = Bbase + h*64;
        glds16(Ah,           sAw);
        glds16(Ah + 1536,    sAw + 8*64);
        glds16(Ah + 2*1536,  sAw + 16*64);
        glds16(Ah + 3*1536,  sAw + 24*64);
        glds16(Bh,           sBw);
        glds16(Bh + 8*512,   sBw + 8*64);
        glds16(Bh + 16*512,  sBw + 16*64);
        glds16(Bh + 24*512,  sBw + 24*64);
        __syncthreads();
        #pragma unroll
        for(int ks=0; ks<2; ks++){
            int kc = ks*4 + quad;
            s16x8 af[4], bfr[4];
            #pragma unroll
            for(int i=0;i<4;i++){
                int r = wm*64 + i*16 + l15;
                af[i] = *(const s16x8*)&sA[r*64 + ((kc ^ (r&7))<<3)];
            }
            #pragma unroll
            for(int j=0;j<4;j++){
                int r = wn*64 + j*16 + l15;
                bfr[j] = *(const s16x8*)&sB[r*64 + ((kc ^ (r&7))<<3)];
            }
            #pragma unroll
            for(int i=0;i<4;i++)
                #pragma unroll
                for(int j=0;j<4;j++)
                    acc[i][j] = __builtin_amdgcn_mfma_f32_16x16x32_bf16(bfr[j], af[i], acc[i][j], 0,0,0);
        }
        __syncthreads();
    }

    // swapped layout: lane holds row = row0+i*16+l15, cols = col0+j*16+quad*4..+3
    int row0 = b*4096 + mr*128 + wm*64;
    int col0 = nt*128 + wn*64;
    float4 bv[4];
    #pragma unroll
    for(int j=0;j<4;j++) bv[j] = *(const float4*)&bias[col0 + j*16 + quad*4];
    #pragma unroll
    for(int i=0;i<4;i++){
        size_t rb = (size_t)(row0 + i*16 + l15)*512 + col0;
        #pragma unroll
        for(int j=0;j<4;j++){
            float4 o;
            o.x = acc[i][j][0] + bv[j].x;
            o.y = acc[i][j][1] + bv[j].y;
            o.z = acc[i][j][2] + bv[j].z;
            o.w = acc[i][j][3] + bv[j].w;
            *(float4*)&out[rb + j*16 + quad*4] = o;
        }
    }
}

extern "C" void kernel_launch(void* const* d_in, const int* in_sizes, int n_in,
                              void* d_out, int out_size, void* d_ws, size_t ws_size,
                              hipStream_t stream){
    const float* x      = (const float*)d_in[0];
    const float* wqkv_w = (const float*)d_in[1];
    const float* wqkv_b = (const float*)d_in[2];
    const float* wp_w   = (const float*)d_in[3];
    const float* wp_b   = (const float*)d_in[4];

    char* ws = (char*)d_ws;
    us*    qkvbf  = (us*)(ws);                    // 96 MB
    us*    xbf    = (us*)(ws + 100663296);        // 32 MB
    float* Spart  = (float*)(ws + 134217728);     // 8 MB
    us*    Wsm    = (us*)(ws + 142606336);        // 0.5 MB
    us*    Mcat   = (us*)(ws + 143130624);        // 4 MB
    us*    wqkvbf = (us*)(ws + 147324928);        // 1.5 MB
    us*    wpbf   = (us*)(ws + 148897792);        // 0.5 MB

    cast_all<<<17408,256,0,stream>>>(x, wqkv_w, wp_w, xbf, wqkvbf, wpbf);

    gemm_qkv<<<3072,256,0,stream>>>(xbf, wqkvbf, wqkv_b, qkvbf);

    attn_scores_mfma<<<dim3(8,64),256,0,stream>>>(qkvbf, Spart);
    softmax64<<<256,256,0,stream>>>(Spart, Wsm);
    fold<<<256,256,0,stream>>>(Wsm, wpbf, Mcat);

    gemm_vout<<<1024,256,0,stream>>>(qkvbf, Mcat, wp_b, (float*)d_out);
}